// Round 1
// baseline (1140.025 us; speedup 1.0000x reference)
//
#include <hip/hip_runtime.h>

#define DEVFN __device__ __forceinline__
#define GLOBAL_AS __attribute__((address_space(1)))
#define LDS_AS __attribute__((address_space(3)))

typedef __attribute__((ext_vector_type(4))) float f32x4;
typedef __attribute__((ext_vector_type(8))) short short8;
typedef __attribute__((ext_vector_type(4))) unsigned int uint4v;
typedef __attribute__((ext_vector_type(8))) unsigned short ushort8;

constexpr int CB = 32;
constexpr int CS = 2048;
constexpr int CD = 1024;
constexpr int CU = 1024;
constexpr int CM = CB * CS;   // 65536

DEVFN unsigned f2bf_u(float f) {
    unsigned u = __float_as_uint(f);
    return (u + 0x7FFFu + ((u >> 16) & 1u)) >> 16;   // RNE f32->bf16
}
DEVFN unsigned f2bf_pack(float lo, float hi) {
    return f2bf_u(lo) | (f2bf_u(hi) << 16);
}
DEVFN float tanh_fast(float x) {
    // tanh(x) = 1 - 2/(1+e^{2x}); exp2-based, saturates correctly at +-inf
    float e = exp2f(x * 2.885390081777927f);
    return 1.0f - 2.0f * __builtin_amdgcn_rcpf(e + 1.0f);
}
DEVFN void async_lds16(const void* g, void* l) {
    __builtin_amdgcn_global_load_lds((const GLOBAL_AS unsigned int*)g,
                                     (LDS_AS unsigned int*)l, 16, 0, 0);
}

// bias[b][u] = b1[u] + b2[u] + sum_d query[b][d] * W2[d][u]
__global__ void k_bias(const float* __restrict__ q, const float* __restrict__ W2,
                       const float* __restrict__ b1, const float* __restrict__ b2,
                       float* __restrict__ bias) {
    int b = blockIdx.y;
    int u = blockIdx.x * 256 + threadIdx.x;
    const float* qb = q + b * CD;
    float acc = b1[u] + b2[u];
#pragma unroll 4
    for (int d = 0; d < CD; ++d) acc += qb[d] * W2[(size_t)d * CU + u];
    bias[b * CU + u] = acc;
}

// Pack W1[D][U] f32 -> bf16 in MFMA-B fragment-linear tiles:
// idx = (kt*4+ut)*8192 + ub*512 + l*8 + j,  d = kt*32 + (l>>4)*8 + j, u = ut*256 + ub*16 + (l&15)
__global__ void k_packW1(const float* __restrict__ W1, unsigned short* __restrict__ W1p) {
    int tid = blockIdx.x * 256 + threadIdx.x;   // 131072 threads, 8 elems each
    int o8  = tid * 8;
    int l   = (o8 >> 3) & 63;
    int ub  = (o8 >> 9) & 15;
    int ut  = (o8 >> 13) & 3;
    int kt  = o8 >> 15;
    int llo = l & 15, lhi = l >> 4;
    int u  = ut * 256 + ub * 16 + llo;
    int d0 = kt * 32 + lhi * 8;
    ushort8 v;
#pragma unroll
    for (int j = 0; j < 8; ++j)
        v[j] = (unsigned short)f2bf_u(W1[(size_t)(d0 + j) * CU + u]);
    *(ushort8*)(W1p + o8) = v;
}

// Fused score GEMM: score4[ut][m] = sum_{u in chunk ut} V[u]*tanh(values[m]@W1[:,u] + bias[b][u])
// BM=128 rows, BN=256 cols/chunk, BK=32, 8 waves, wave tile 64x64 (4x4 MFMA 16x16x32 frags)
__global__ __launch_bounds__(512, 6) void k_score(
    const float* __restrict__ values, const unsigned short* __restrict__ W1p,
    const float* __restrict__ bias, const float* __restrict__ V,
    float* __restrict__ score4) {
    __shared__ __align__(16) char smem[49152];   // As 2*8192 | Bs 2*16384

    const int t = threadIdx.x;
    const int w = t >> 6, l = t & 63;
    const int wr = w >> 2, wc = w & 3;
    const int ut = blockIdx.x;            // N-chunk 0..3
    const int m0 = blockIdx.y * 128;
    const int u0 = ut * 256;
    const int bb = m0 >> 11;              // batch index (BM=128 divides S)

    // A staging: thread -> (row ar, 16B chunk ac), swizzled LDS write
    const int ar = t >> 2, ac = t & 3;
    const float* aSrc = values + (size_t)(m0 + ar) * CD + ac * 8;
    const int aWr = ar * 64 + ((ac * 16) ^ (((ar >> 1) & 3) << 4));

    // fragment read offsets
    int aRd[4];
#pragma unroll
    for (int i = 0; i < 4; ++i) {
        int r = wr * 64 + i * 16 + (l & 15);
        aRd[i] = r * 64 + ((((l >> 4) * 16)) ^ (((r >> 1) & 3) << 4));
    }
    int bRd[4];
#pragma unroll
    for (int j = 0; j < 4; ++j) bRd[j] = (wc * 4 + j) * 1024 + l * 16;

    f32x4 zero4 = {0.f, 0.f, 0.f, 0.f};
    f32x4 acc[4][4];
#pragma unroll
    for (int i = 0; i < 4; ++i)
#pragma unroll
        for (int j = 0; j < 4; ++j) acc[i][j] = zero4;

    f32x4 av0, av1;

    auto loadA = [&](int kt) {
        const f32x4* p = (const f32x4*)(aSrc + kt * 32);
        av0 = p[0]; av1 = p[1];
    };
    auto writeA = [&](int buf) {
        uint4v pk;
        pk[0] = f2bf_pack(av0[0], av0[1]);
        pk[1] = f2bf_pack(av0[2], av0[3]);
        pk[2] = f2bf_pack(av1[0], av1[1]);
        pk[3] = f2bf_pack(av1[2], av1[3]);
        *(uint4v*)(smem + buf * 8192 + aWr) = pk;
    };
    auto stageB = [&](int buf, int kt) {
        const unsigned short* bt = W1p + (size_t)(kt * 4 + ut) * 8192;
#pragma unroll
        for (int qq = 0; qq < 2; ++qq) {
            int inst = w * 2 + qq;
            async_lds16(bt + inst * 512 + l * 8,
                        smem + 16384 + buf * 16384 + inst * 1024);
        }
    };

    loadA(0);
    stageB(0, 0);
    writeA(0);
    __syncthreads();

#pragma unroll 2
    for (int kt = 0; kt < 32; ++kt) {
        int cur = kt & 1, nxt = cur ^ 1;
        if (kt < 31) { loadA(kt + 1); stageB(nxt, kt + 1); }

        short8 aF[4], bF[4];
#pragma unroll
        for (int i = 0; i < 4; ++i)
            aF[i] = *(const short8*)(smem + cur * 8192 + aRd[i]);
#pragma unroll
        for (int j = 0; j < 4; ++j)
            bF[j] = *(const short8*)(smem + 16384 + cur * 16384 + bRd[j]);
#pragma unroll
        for (int i = 0; i < 4; ++i)
#pragma unroll
            for (int j = 0; j < 4; ++j)
                acc[i][j] = __builtin_amdgcn_mfma_f32_16x16x32_bf16(
                    aF[i], bF[j], acc[i][j], 0, 0, 0);

        if (kt < 31) writeA(nxt);
        __syncthreads();
    }

    // epilogue: part[i][rr] = sum over this wave's 64 cols of V[u]*tanh(z)
    float part[4][4];
#pragma unroll
    for (int i = 0; i < 4; ++i)
#pragma unroll
        for (int rr = 0; rr < 4; ++rr) part[i][rr] = 0.f;

#pragma unroll
    for (int j = 0; j < 4; ++j) {
        int col = u0 + wc * 64 + j * 16 + (l & 15);
        float vv = V[col];
        float bz = bias[bb * CU + col];
#pragma unroll
        for (int i = 0; i < 4; ++i)
#pragma unroll
            for (int rr = 0; rr < 4; ++rr)
                part[i][rr] += vv * tanh_fast(acc[i][j][rr] + bz);
    }

    float* sred = (float*)smem;   // 512 floats, reuse As area (all waves past final barrier)
#pragma unroll
    for (int i = 0; i < 4; ++i)
#pragma unroll
        for (int rr = 0; rr < 4; ++rr) {
            float v = part[i][rr];
            v += __shfl_xor(v, 1);
            v += __shfl_xor(v, 2);
            v += __shfl_xor(v, 4);
            v += __shfl_xor(v, 8);
            if ((l & 15) == 0)
                sred[wc * 128 + wr * 64 + i * 16 + (l >> 4) * 4 + rr] = v;
        }
    __syncthreads();
    if (t < 128) {
        float s = sred[t] + sred[128 + t] + sred[256 + t] + sred[384 + t];
        score4[(size_t)ut * CM + m0 + t] = s;
    }
}

// softmax over S per batch; sums the 4 N-chunk score slices
__global__ void k_softmax(const float* __restrict__ score4, float* __restrict__ wts) {
    int b = blockIdx.x, t = threadIdx.x;   // 1024 threads
    int i0 = b * CS + t, i1 = i0 + 1024;
    float s0 = score4[i0] + score4[CM + i0] + score4[2 * CM + i0] + score4[3 * CM + i0];
    float s1 = score4[i1] + score4[CM + i1] + score4[2 * CM + i1] + score4[3 * CM + i1];
    __shared__ float red[16];
    int wv = t >> 6, ln = t & 63;
    float m = fmaxf(s0, s1);
#pragma unroll
    for (int o = 32; o >= 1; o >>= 1) m = fmaxf(m, __shfl_xor(m, o));
    if (ln == 0) red[wv] = m;
    __syncthreads();
    float M = red[0];
#pragma unroll
    for (int k = 1; k < 16; ++k) M = fmaxf(M, red[k]);
    float e0 = __expf(s0 - M), e1 = __expf(s1 - M);
    float sm = e0 + e1;
#pragma unroll
    for (int o = 32; o >= 1; o >>= 1) sm += __shfl_xor(sm, o);
    __syncthreads();
    if (ln == 0) red[wv] = sm;
    __syncthreads();
    float T = 0.f;
#pragma unroll
    for (int k = 0; k < 16; ++k) T += red[k];
    float inv = 1.0f / T;
    wts[i0] = e0 * inv;
    wts[i1] = e1 * inv;
}

// context partials: part[b][sc][d] = sum_{s in chunk} w[b][s]*values[b][s][d]
__global__ void k_ctx_part(const float* __restrict__ values, const float* __restrict__ wts,
                           float* __restrict__ part) {
    int b = blockIdx.y, sc = blockIdx.x;   // 32 x 32
    int t = threadIdx.x;                    // 256, float4 each -> full D
    const float* vb = values + ((size_t)b * CS + sc * 64) * CD + t * 4;
    const float* wb = wts + b * CS + sc * 64;
    f32x4 a = {0.f, 0.f, 0.f, 0.f};
#pragma unroll 4
    for (int s = 0; s < 64; ++s) {
        float wgt = wb[s];
        f32x4 v = *(const f32x4*)(vb + (size_t)s * CD);
        a += v * wgt;
    }
    *(f32x4*)(part + (size_t)(b * 32 + sc) * CD + t * 4) = a;
}

__global__ void k_ctx_red(const float* __restrict__ part, float* __restrict__ ctx) {
    int idx = blockIdx.x * 256 + threadIdx.x;   // 32768
    int b = idx >> 10, d = idx & 1023;
    float s = 0.f;
#pragma unroll 8
    for (int c = 0; c < 32; ++c) s += part[(size_t)(b * 32 + c) * CD + d];
    ctx[idx] = s;
}

extern "C" void kernel_launch(void* const* d_in, const int* in_sizes, int n_in,
                              void* d_out, int out_size, void* d_ws, size_t ws_size,
                              hipStream_t stream) {
    const float* query  = (const float*)d_in[0];
    const float* values = (const float*)d_in[1];
    const float* W1     = (const float*)d_in[2];
    const float* b1     = (const float*)d_in[3];
    const float* W2     = (const float*)d_in[4];
    const float* b2     = (const float*)d_in[5];
    const float* V      = (const float*)d_in[6];
    // d_in[7] = bV: softmax is shift-invariant and score is not an output -> unused

    float* out = (float*)d_out;
    float* ctx = out;            // [32][1024]
    float* wts = out + 32768;    // [32][2048]

    char* ws = (char*)d_ws;
    float*          score4 = (float*)ws;                                   // 1 MB
    float*          bias   = (float*)(ws + (1 << 20));                     // 128 KB
    unsigned short* W1p    = (unsigned short*)(ws + (1 << 20) + (1 << 17)); // 2 MB
    float*          part   = (float*)(ws + (1 << 20) + (1 << 17) + (1 << 21)); // 4 MB

    k_bias<<<dim3(4, 32), 256, 0, stream>>>(query, W2, b1, b2, bias);
    k_packW1<<<512, 256, 0, stream>>>(W1, W1p);
    k_score<<<dim3(4, 512), 512, 0, stream>>>(values, W1p, bias, V, score4);
    k_softmax<<<32, 1024, 0, stream>>>(score4, wts);
    k_ctx_part<<<dim3(32, 32), 256, 0, stream>>>(values, wts, part);
    k_ctx_red<<<128, 256, 0, stream>>>(part, ctx);
}

// Round 2
// 388.757 us; speedup vs baseline: 2.9325x; 2.9325x over previous
//
#include <hip/hip_runtime.h>

#define DEVFN __device__ __forceinline__
#define GLOBAL_AS __attribute__((address_space(1)))
#define LDS_AS __attribute__((address_space(3)))

typedef __attribute__((ext_vector_type(4))) float f32x4;
typedef __attribute__((ext_vector_type(8))) short short8;
typedef __attribute__((ext_vector_type(4))) unsigned int uint4v;
typedef __attribute__((ext_vector_type(8))) unsigned short ushort8;

constexpr int CB = 32;
constexpr int CS = 2048;
constexpr int CD = 1024;
constexpr int CU = 1024;
constexpr int CM = CB * CS;   // 65536

DEVFN unsigned f2bf_u(float f) {
    unsigned u = __float_as_uint(f);
    return (u + 0x7FFFu + ((u >> 16) & 1u)) >> 16;   // RNE f32->bf16
}
DEVFN unsigned f2bf_pack(float lo, float hi) {
    return f2bf_u(lo) | (f2bf_u(hi) << 16);
}
DEVFN float tanh_fast(float x) {
    float e = exp2f(x * 2.885390081777927f);
    return 1.0f - 2.0f * __builtin_amdgcn_rcpf(e + 1.0f);
}
DEVFN void async_lds16(const void* g, void* l) {
    __builtin_amdgcn_global_load_lds((const GLOBAL_AS unsigned int*)g,
                                     (LDS_AS unsigned int*)l, 16, 0, 0);
}

// bias[b][u] = b1[u] + b2[u] + sum_d query[b][d] * W2[d][u]
__global__ void k_bias(const float* __restrict__ q, const float* __restrict__ W2,
                       const float* __restrict__ b1, const float* __restrict__ b2,
                       float* __restrict__ bias) {
    int b = blockIdx.y;
    int u = blockIdx.x * 256 + threadIdx.x;
    const float* qb = q + b * CD;
    float acc = b1[u] + b2[u];
#pragma unroll 4
    for (int d = 0; d < CD; ++d) acc += qb[d] * W2[(size_t)d * CU + u];
    bias[b * CU + u] = acc;
}

// Pack W1[D][U] f32 -> bf16, MFMA-B fragment-linear tiles:
// idx = (kt*4+ut)*8192 + ub*512 + l*8 + j ; d = kt*32 + (l>>4)*8 + j ; u = ut*256 + ub*16 + (l&15)
__global__ void k_packW1(const float* __restrict__ W1, unsigned short* __restrict__ W1p) {
    int tid = blockIdx.x * 256 + threadIdx.x;   // 131072 threads, 8 elems each
    int o8  = tid * 8;
    int l   = (o8 >> 3) & 63;
    int ub  = (o8 >> 9) & 15;
    int ut  = (o8 >> 13) & 3;
    int kt  = o8 >> 15;
    int u  = ut * 256 + ub * 16 + (l & 15);
    int d0 = kt * 32 + (l >> 4) * 8;
    ushort8 v;
#pragma unroll
    for (int j = 0; j < 8; ++j)
        v[j] = (unsigned short)f2bf_u(W1[(size_t)(d0 + j) * CU + u]);
    *(ushort8*)(W1p + o8) = v;
}

// Fused score GEMM, BM=64 x full U=1024, BK=32, 8 waves (each 64 rows x 128 cols).
// A staged as f32 (frag-linear, 2 half-k regions), B staged bf16 frag-linear.
// Counted vmcnt(9) + raw barriers: loads stay in flight across barriers.
__global__ __launch_bounds__(512, 2) void k_score(
    const float* __restrict__ values, const unsigned short* __restrict__ W1p,
    const float* __restrict__ bias, const float* __restrict__ V,
    float* __restrict__ score) {
    // [A0 8K][A1 8K][B0 64K][B1 64K] = 144 KB
    __shared__ __align__(16) char smem[147456];

    const int t = threadIdx.x;
    const int w = t >> 6, l = t & 63;
    const int m0 = blockIdx.x * 64;
    const int bb = m0 >> 11;              // batch (64 divides S)

    // A stage: wave w stages chunk w -> lds slot w*1024 (h = w>>2, i = w&3)
    // element at lane l, 16B unit: row = (w&3)*16 + (l&15), k = (l>>4)*8 + (w>>2)*4
    const float* aSrc = values + (size_t)(m0 + (w & 3) * 16 + (l & 15)) * CD
                        + ((l >> 4) * 8 + (w >> 2) * 4);
    // B stage: wave w stages insts w*8+q -> contiguous 64KB of kt-chunk
    const unsigned short* bSrc = W1p + w * 4096 + l * 8;

    auto stage = [&](int buf, int kt) {
        async_lds16(aSrc + (size_t)kt * 32, smem + buf * 8192 + w * 1024);
        const unsigned short* bs = bSrc + (size_t)kt * 32768;
        char* bl = smem + 16384 + buf * 65536 + w * 8192;
#pragma unroll
        for (int q = 0; q < 8; ++q)
            async_lds16(bs + q * 512, bl + q * 1024);
    };

    f32x4 zero4 = {0.f, 0.f, 0.f, 0.f};
    f32x4 acc[4][8];
#pragma unroll
    for (int i = 0; i < 4; ++i)
#pragma unroll
        for (int j = 0; j < 8; ++j) acc[i][j] = zero4;

    auto compute = [&](int buf) {
        const char* aB = smem + buf * 8192;
        const char* bB = smem + 16384 + buf * 65536 + (w >> 1) * 16384 + (w & 1) * 8192;
        short8 bF[8];
#pragma unroll
        for (int j = 0; j < 8; ++j)
            bF[j] = *(const short8*)(bB + j * 1024 + l * 16);
        short8 aF[4];
#pragma unroll
        for (int i = 0; i < 4; ++i) {
            f32x4 x0 = *(const f32x4*)(aB + i * 1024 + l * 16);
            f32x4 x1 = *(const f32x4*)(aB + 4096 + i * 1024 + l * 16);
            uint4v p;
            p[0] = f2bf_pack(x0[0], x0[1]);
            p[1] = f2bf_pack(x0[2], x0[3]);
            p[2] = f2bf_pack(x1[0], x1[1]);
            p[3] = f2bf_pack(x1[2], x1[3]);
            aF[i] = __builtin_bit_cast(short8, p);
        }
#pragma unroll
        for (int i = 0; i < 4; ++i)
#pragma unroll
            for (int j = 0; j < 8; ++j)
                acc[i][j] = __builtin_amdgcn_mfma_f32_16x16x32_bf16(
                    aF[i], bF[j], acc[i][j], 0, 0, 0);
    };

    stage(0, 0);
    for (int kt = 0; kt < 31; ++kt) {
        int cur = kt & 1;
        stage(cur ^ 1, kt + 1);                       // 9 loads -> in flight
        asm volatile("s_waitcnt vmcnt(9)" ::: "memory");  // cur fully landed
        asm volatile("s_barrier" ::: "memory");
        compute(cur);
        asm volatile("s_barrier" ::: "memory");       // all reads of cur done
    }
    asm volatile("s_waitcnt vmcnt(0)" ::: "memory");
    asm volatile("s_barrier" ::: "memory");
    compute(1);   // kt = 31

    // epilogue: score[m0+r] = sum_u V[u]*tanh(z[r][u] + bias[bb][u])
    float part[4][4];
#pragma unroll
    for (int i = 0; i < 4; ++i)
#pragma unroll
        for (int rr = 0; rr < 4; ++rr) part[i][rr] = 0.f;

#pragma unroll
    for (int j = 0; j < 8; ++j) {
        int col = w * 128 + j * 16 + (l & 15);
        float vv = V[col];
        float bz = bias[bb * CU + col];
#pragma unroll
        for (int i = 0; i < 4; ++i)
#pragma unroll
            for (int rr = 0; rr < 4; ++rr)
                part[i][rr] += vv * tanh_fast(acc[i][j][rr] + bz);
    }

    __syncthreads();
    float* red = (float*)smem;    // [8][64] f32, reuse A region
#pragma unroll
    for (int i = 0; i < 4; ++i)
#pragma unroll
        for (int rr = 0; rr < 4; ++rr) {
            float v = part[i][rr];
            v += __shfl_xor(v, 1);
            v += __shfl_xor(v, 2);
            v += __shfl_xor(v, 4);
            v += __shfl_xor(v, 8);
            if ((l & 15) == 0)
                red[w * 64 + i * 16 + (l >> 4) * 4 + rr] = v;
        }
    __syncthreads();
    if (t < 64) {
        float s = 0.f;
#pragma unroll
        for (int ww = 0; ww < 8; ++ww) s += red[ww * 64 + t];
        score[m0 + t] = s;
    }
}

// softmax over S per batch
__global__ void k_softmax(const float* __restrict__ score, float* __restrict__ wts) {
    int b = blockIdx.x, t = threadIdx.x;   // 1024 threads
    int i0 = b * CS + t, i1 = i0 + 1024;
    float s0 = score[i0];
    float s1 = score[i1];
    __shared__ float red[16];
    int wv = t >> 6, ln = t & 63;
    float m = fmaxf(s0, s1);
#pragma unroll
    for (int o = 32; o >= 1; o >>= 1) m = fmaxf(m, __shfl_xor(m, o));
    if (ln == 0) red[wv] = m;
    __syncthreads();
    float M = red[0];
#pragma unroll
    for (int k = 1; k < 16; ++k) M = fmaxf(M, red[k]);
    float e0 = __expf(s0 - M), e1 = __expf(s1 - M);
    float sm = e0 + e1;
#pragma unroll
    for (int o = 32; o >= 1; o >>= 1) sm += __shfl_xor(sm, o);
    __syncthreads();
    if (ln == 0) red[wv] = sm;
    __syncthreads();
    float T = 0.f;
#pragma unroll
    for (int k = 0; k < 16; ++k) T += red[k];
    float inv = 1.0f / T;
    wts[i0] = e0 * inv;
    wts[i1] = e1 * inv;
}

// context partials: part[b][sc][d] = sum_{s in chunk} w[b][s]*values[b][s][d]
__global__ void k_ctx_part(const float* __restrict__ values, const float* __restrict__ wts,
                           float* __restrict__ part) {
    int b = blockIdx.y, sc = blockIdx.x;   // 32 x 32
    int t = threadIdx.x;                    // 256, float4 each -> full D
    const float* vb = values + ((size_t)b * CS + sc * 64) * CD + t * 4;
    const float* wb = wts + b * CS + sc * 64;
    f32x4 a = {0.f, 0.f, 0.f, 0.f};
#pragma unroll 4
    for (int s = 0; s < 64; ++s) {
        float wgt = wb[s];
        f32x4 v = *(const f32x4*)(vb + (size_t)s * CD);
        a += v * wgt;
    }
    *(f32x4*)(part + (size_t)(b * 32 + sc) * CD + t * 4) = a;
}

__global__ void k_ctx_red(const float* __restrict__ part, float* __restrict__ ctx) {
    int idx = blockIdx.x * 256 + threadIdx.x;   // 32768
    int b = idx >> 10, d = idx & 1023;
    float s = 0.f;
#pragma unroll 8
    for (int c = 0; c < 32; ++c) s += part[(size_t)(b * 32 + c) * CD + d];
    ctx[idx] = s;
}

extern "C" void kernel_launch(void* const* d_in, const int* in_sizes, int n_in,
                              void* d_out, int out_size, void* d_ws, size_t ws_size,
                              hipStream_t stream) {
    const float* query  = (const float*)d_in[0];
    const float* values = (const float*)d_in[1];
    const float* W1     = (const float*)d_in[2];
    const float* b1     = (const float*)d_in[3];
    const float* W2     = (const float*)d_in[4];
    const float* b2     = (const float*)d_in[5];
    const float* V      = (const float*)d_in[6];
    // d_in[7] = bV: softmax shift-invariant, score not an output -> unused

    float* out = (float*)d_out;
    float* ctx = out;            // [32][1024]
    float* wts = out + 32768;    // [32][2048]

    char* ws = (char*)d_ws;
    float*          score = (float*)ws;                                        // 256 KB (1 MB reserved)
    float*          bias  = (float*)(ws + (1 << 20));                          // 128 KB
    unsigned short* W1p   = (unsigned short*)(ws + (1 << 20) + (1 << 17));     // 2 MB
    float*          part  = (float*)(ws + (1 << 20) + (1 << 17) + (1 << 21));  // 4 MB

    k_bias<<<dim3(4, 32), 256, 0, stream>>>(query, W2, b1, b2, bias);
    k_packW1<<<512, 256, 0, stream>>>(W1, W1p);
    k_score<<<1024, 512, 0, stream>>>(values, W1p, bias, V, score);
    k_softmax<<<32, 1024, 0, stream>>>(score, wts);
    k_ctx_part<<<dim3(32, 32), 256, 0, stream>>>(values, wts, part);
    k_ctx_red<<<128, 256, 0, stream>>>(part, ctx);
}

// Round 3
// 268.527 us; speedup vs baseline: 4.2455x; 1.4477x over previous
//
#include <hip/hip_runtime.h>

#define DEVFN __device__ __forceinline__
#define GLOBAL_AS __attribute__((address_space(1)))
#define LDS_AS __attribute__((address_space(3)))

typedef __attribute__((ext_vector_type(4))) float f32x4;
typedef __attribute__((ext_vector_type(8))) short short8;
typedef __attribute__((ext_vector_type(8))) unsigned short ushort8;

constexpr int CB = 32;
constexpr int CS = 2048;
constexpr int CD = 1024;
constexpr int CU = 1024;
constexpr int CM = CB * CS;   // 65536

DEVFN unsigned f2bf_u(float f) {
    unsigned u = __float_as_uint(f);
    return (u + 0x7FFFu + ((u >> 16) & 1u)) >> 16;   // RNE f32->bf16
}
DEVFN unsigned f2bf_pack(float lo, float hi) {
    return f2bf_u(lo) | (f2bf_u(hi) << 16);
}
DEVFN float tanh_fast(float x) {
    float e = exp2f(x * 2.885390081777927f);
    return 1.0f - 2.0f * __builtin_amdgcn_rcpf(e + 1.0f);
}
DEVFN void async_lds16(const void* g, void* l) {
    __builtin_amdgcn_global_load_lds((const GLOBAL_AS unsigned int*)g,
                                     (LDS_AS unsigned int*)l, 16, 0, 0);
}

// ---- bias = b1 + b2 + q@W2, two-stage split-D for parallelism ----
__global__ void k_bias1(const float* __restrict__ q, const float* __restrict__ W2,
                        float* __restrict__ bpart) {
    int dc = blockIdx.x, b = blockIdx.y;   // 8 x 32
    int t = threadIdx.x;                    // 256
    __shared__ float qs[128];
    if (t < 128) qs[t] = q[b * CD + dc * 128 + t];
    __syncthreads();
    float acc0 = 0.f, acc1 = 0.f, acc2 = 0.f, acc3 = 0.f;
    const float* w2 = W2 + (size_t)(dc * 128) * CU + t;
#pragma unroll 4
    for (int d = 0; d < 128; ++d) {
        float qv = qs[d];
        const float* r = w2 + (size_t)d * CU;
        acc0 += qv * r[0];
        acc1 += qv * r[256];
        acc2 += qv * r[512];
        acc3 += qv * r[768];
    }
    float* o = bpart + (size_t)(b * 8 + dc) * CU + t;
    o[0] = acc0; o[256] = acc1; o[512] = acc2; o[768] = acc3;
}

__global__ void k_bias2(const float* __restrict__ bpart, const float* __restrict__ b1,
                        const float* __restrict__ b2, float* __restrict__ bias) {
    int idx = blockIdx.x * 256 + threadIdx.x;   // 32768
    int b = idx >> 10, u = idx & 1023;
    float s = b1[u] + b2[u];
#pragma unroll
    for (int dc = 0; dc < 8; ++dc) s += bpart[(size_t)(b * 8 + dc) * CU + u];
    bias[idx] = s;
}

// ---- pack W1[D][U] f32 -> bf16, MFMA-B fragment-linear tiles ----
// idx = (kt*4+ut)*8192 + ub*512 + l*8 + j ; d = kt*32 + (l>>4)*8 + j ; u = ut*256 + ub*16 + (l&15)
__global__ void k_packW1(const float* __restrict__ W1, unsigned short* __restrict__ W1p) {
    int tid = blockIdx.x * 256 + threadIdx.x;   // 131072 threads, 8 elems each
    int o8  = tid * 8;
    int l   = (o8 >> 3) & 63;
    int ub  = (o8 >> 9) & 15;
    int ut  = (o8 >> 13) & 3;
    int kt  = o8 >> 15;
    int u  = ut * 256 + ub * 16 + (l & 15);
    int d0 = kt * 32 + (l >> 4) * 8;
    ushort8 v;
#pragma unroll
    for (int j = 0; j < 8; ++j)
        v[j] = (unsigned short)f2bf_u(W1[(size_t)(d0 + j) * CU + u]);
    *(ushort8*)(W1p + o8) = v;
}

// ---- fused score GEMM: BM=64 x U=1024, BK=32, 8 waves (64 rows x 128 cols each).
// A: reg-staged f32 -> bf16 frag-linear LDS (T14 issue-early/write-late).
// B: gload_lds, frag-linear. Counted vmcnt, loads in flight across barriers.
__global__ __launch_bounds__(512, 2) void k_score(
    const float* __restrict__ values, const unsigned short* __restrict__ W1p,
    const float* __restrict__ bias, const float* __restrict__ V,
    float* __restrict__ score) {
    // [A0 4K][A1 4K][B0 64K][B1 64K] = 136 KB
    __shared__ __align__(16) char smem[139264];

    const int t = threadIdx.x;
    const int w = t >> 6, l = t & 63;
    const int w8 = w * 8;
    const int m0 = blockIdx.x * 64;
    const int bb = m0 >> 11;              // batch (64 divides S)

    // A stage: thread t loads values[m0 + t/8][kt*32 + (t&7)*4 ..+4] (f32x4)
    const float* aSrcT = values + (size_t)(m0 + (t >> 3)) * CD + (t & 7) * 4;
    // frag-linear bf16 write slot: frag i=row>>4, lane=(row&15)|((k>>3)<<4), byte within = (k&7)*2
    const int aWrByte = (t >> 7) * 1024
                      + (((t >> 3) & 15) | (((t >> 1) & 3) << 4)) * 16
                      + (t & 1) * 8;
    // B: wave w stages insts w8+q ; reads its col block
    const unsigned short* bSrc = W1p + (size_t)w8 * 512 + l * 8;
    const int bRdBase = (w >> 1) * 16384 + (w & 1) * 8192;

    f32x4 zero4 = {0.f, 0.f, 0.f, 0.f};
    f32x4 acc[4][8];
#pragma unroll
    for (int i = 0; i < 4; ++i)
#pragma unroll
        for (int j = 0; j < 8; ++j) acc[i][j] = zero4;

    f32x4 aH0, aH1;

    // prologue: B(0) -> buf0 ; A(0),A(1) -> regs ; write A(0) -> buf0
    {
        char* bl = smem + 8192 + w8 * 1024;
#pragma unroll
        for (int q = 0; q < 8; ++q) async_lds16(bSrc + q * 512, bl + q * 1024);
        aH0 = *(const f32x4*)(aSrcT);
        aH1 = *(const f32x4*)(aSrcT + 32);
        uint2 pk;
        pk.x = f2bf_pack(aH0[0], aH0[1]);
        pk.y = f2bf_pack(aH0[2], aH0[3]);
        *(uint2*)(smem + aWrByte) = pk;
    }

#define SCORE_BODY(KT, AH_LD, AH_WR, DO_LD, DO_STAGE, DO_WR)                        \
    {                                                                               \
        const int cur = (KT) & 1, nxt = cur ^ 1;                                    \
        asm volatile("s_waitcnt vmcnt(1)" ::: "memory");                            \
        asm volatile("s_waitcnt lgkmcnt(0)" ::: "memory");                          \
        asm volatile("s_barrier" ::: "memory");                                     \
        __builtin_amdgcn_sched_barrier(0);                                          \
        if (DO_STAGE) {                                                             \
            const unsigned short* bs = bSrc + (size_t)((KT) + 1) * 32768;           \
            char* bl = smem + 8192 + nxt * 65536 + w8 * 1024;                       \
            _Pragma("unroll")                                                       \
            for (int q = 0; q < 8; ++q) async_lds16(bs + q * 512, bl + q * 1024);   \
        }                                                                           \
        if (DO_LD) AH_LD = *(const f32x4*)(aSrcT + ((KT) + 2) * 32);                \
        __builtin_amdgcn_sched_barrier(0);                                          \
        const char* aB = smem + cur * 4096;                                         \
        const char* bB = smem + 8192 + cur * 65536 + bRdBase;                       \
        short8 aF[4], bF[8];                                                        \
        _Pragma("unroll")                                                           \
        for (int i = 0; i < 4; ++i)                                                 \
            aF[i] = *(const short8*)(aB + i * 1024 + l * 16);                       \
        _Pragma("unroll")                                                           \
        for (int j = 0; j < 8; ++j)                                                 \
            bF[j] = *(const short8*)(bB + j * 1024 + l * 16);                       \
        __builtin_amdgcn_s_setprio(1);                                              \
        _Pragma("unroll")                                                           \
        for (int i = 0; i < 4; ++i)                                                 \
            _Pragma("unroll")                                                       \
            for (int j = 0; j < 8; ++j)                                             \
                acc[i][j] = __builtin_amdgcn_mfma_f32_16x16x32_bf16(                \
                    aF[i], bF[j], acc[i][j], 0, 0, 0);                              \
        __builtin_amdgcn_s_setprio(0);                                              \
        __builtin_amdgcn_sched_barrier(0);                                          \
        if (DO_WR) {                                                                \
            uint2 pk;                                                               \
            pk.x = f2bf_pack(AH_WR[0], AH_WR[1]);                                   \
            pk.y = f2bf_pack(AH_WR[2], AH_WR[3]);                                   \
            *(uint2*)(smem + nxt * 4096 + aWrByte) = pk;                            \
        }                                                                           \
    }

    for (int kt = 0; kt < 30; kt += 2) {
        SCORE_BODY(kt,     aH0, aH1, true, true, true)      // even: load A(kt+2)->aH0, write A(kt+1)=aH1
        SCORE_BODY(kt + 1, aH1, aH0, true, true, true)      // odd:  load A(kt+3)->aH1, write A(kt+2)=aH0
    }
    SCORE_BODY(30, aH0, aH1, false, true, true)             // stage B(31), write A(31)=aH1
    SCORE_BODY(31, aH0, aH0, false, false, false)
#undef SCORE_BODY

    // epilogue: score[m0+r] = sum_u V[u]*tanh(z[r][u] + bias[bb][u])
    float part[4][4];
#pragma unroll
    for (int i = 0; i < 4; ++i)
#pragma unroll
        for (int rr = 0; rr < 4; ++rr) part[i][rr] = 0.f;

#pragma unroll
    for (int j = 0; j < 8; ++j) {
        int col = w * 128 + j * 16 + (l & 15);
        float vv = V[col];
        float bz = bias[bb * CU + col];
#pragma unroll
        for (int i = 0; i < 4; ++i)
#pragma unroll
            for (int rr = 0; rr < 4; ++rr)
                part[i][rr] += vv * tanh_fast(acc[i][j][rr] + bz);
    }

    __syncthreads();
    float* red = (float*)smem;    // [8][64] f32
#pragma unroll
    for (int i = 0; i < 4; ++i)
#pragma unroll
        for (int rr = 0; rr < 4; ++rr) {
            float v = part[i][rr];
            v += __shfl_xor(v, 1);
            v += __shfl_xor(v, 2);
            v += __shfl_xor(v, 4);
            v += __shfl_xor(v, 8);
            if ((l & 15) == 0)
                red[w * 64 + i * 16 + (l >> 4) * 4 + rr] = v;
        }
    __syncthreads();
    if (t < 64) {
        float s = 0.f;
#pragma unroll
        for (int ww = 0; ww < 8; ++ww) s += red[ww * 64 + t];
        score[m0 + t] = s;
    }
}

// ---- softmax over S per batch ----
__global__ void k_softmax(const float* __restrict__ score, float* __restrict__ wts) {
    int b = blockIdx.x, t = threadIdx.x;   // 1024 threads
    int i0 = b * CS + t, i1 = i0 + 1024;
    float s0 = score[i0];
    float s1 = score[i1];
    __shared__ float red[16];
    int wv = t >> 6, ln = t & 63;
    float m = fmaxf(s0, s1);
#pragma unroll
    for (int o = 32; o >= 1; o >>= 1) m = fmaxf(m, __shfl_xor(m, o));
    if (ln == 0) red[wv] = m;
    __syncthreads();
    float M = red[0];
#pragma unroll
    for (int k = 1; k < 16; ++k) M = fmaxf(M, red[k]);
    float e0 = __expf(s0 - M), e1 = __expf(s1 - M);
    float sm = e0 + e1;
#pragma unroll
    for (int o = 32; o >= 1; o >>= 1) sm += __shfl_xor(sm, o);
    __syncthreads();
    if (ln == 0) red[wv] = sm;
    __syncthreads();
    float T = 0.f;
#pragma unroll
    for (int k = 0; k < 16; ++k) T += red[k];
    float inv = 1.0f / T;
    wts[i0] = e0 * inv;
    wts[i1] = e1 * inv;
}

// ---- context ----
__global__ void k_ctx_part(const float* __restrict__ values, const float* __restrict__ wts,
                           float* __restrict__ part) {
    int b = blockIdx.y, sc = blockIdx.x;   // 32 x 32
    int t = threadIdx.x;                    // 256, float4 each -> full D
    const float* vb = values + ((size_t)b * CS + sc * 64) * CD + t * 4;
    const float* wb = wts + b * CS + sc * 64;
    f32x4 a = {0.f, 0.f, 0.f, 0.f};
#pragma unroll 8
    for (int s = 0; s < 64; ++s) {
        float wgt = wb[s];
        f32x4 v = *(const f32x4*)(vb + (size_t)s * CD);
        a += v * wgt;
    }
    *(f32x4*)(part + (size_t)(b * 32 + sc) * CD + t * 4) = a;
}

__global__ void k_ctx_red(const float* __restrict__ part, float* __restrict__ ctx) {
    int idx = blockIdx.x * 256 + threadIdx.x;   // 32768
    int b = idx >> 10, d = idx & 1023;
    float s = 0.f;
#pragma unroll 8
    for (int c = 0; c < 32; ++c) s += part[(size_t)(b * 32 + c) * CD + d];
    ctx[idx] = s;
}

extern "C" void kernel_launch(void* const* d_in, const int* in_sizes, int n_in,
                              void* d_out, int out_size, void* d_ws, size_t ws_size,
                              hipStream_t stream) {
    const float* query  = (const float*)d_in[0];
    const float* values = (const float*)d_in[1];
    const float* W1     = (const float*)d_in[2];
    const float* b1     = (const float*)d_in[3];
    const float* W2     = (const float*)d_in[4];
    const float* b2     = (const float*)d_in[5];
    const float* V      = (const float*)d_in[6];
    // d_in[7] = bV: softmax shift-invariant, score not an output -> unused

    float* out = (float*)d_out;
    float* ctx = out;            // [32][1024]
    float* wts = out + 32768;    // [32][2048]

    char* ws = (char*)d_ws;
    float*          score = (float*)ws;                                        // 256 KB (1 MB reserved)
    float*          bias  = (float*)(ws + (1 << 20));                          // 128 KB
    unsigned short* W1p   = (unsigned short*)(ws + (1 << 20) + (1 << 17));     // 2 MB
    float*          part  = (float*)(ws + (1 << 20) + (1 << 17) + (1 << 21));  // 4 MB (also bias_part early)
    float*          bpart = part;   // 32x8x1024 f32 = 1 MB, consumed before k_ctx_part

    k_bias1<<<dim3(8, 32), 256, 0, stream>>>(query, W2, bpart);
    k_bias2<<<128, 256, 0, stream>>>(bpart, b1, b2, bias);
    k_packW1<<<512, 256, 0, stream>>>(W1, W1p);
    k_score<<<1024, 512, 0, stream>>>(values, W1p, bias, V, score);
    k_softmax<<<32, 1024, 0, stream>>>(score, wts);
    k_ctx_part<<<dim3(32, 32), 256, 0, stream>>>(values, wts, part);
    k_ctx_red<<<128, 256, 0, stream>>>(part, ctx);
}

// Round 4
// 235.765 us; speedup vs baseline: 4.8354x; 1.1390x over previous
//
#include <hip/hip_runtime.h>

#define DEVFN __device__ __forceinline__
#define GLOBAL_AS __attribute__((address_space(1)))
#define LDS_AS __attribute__((address_space(3)))

typedef __attribute__((ext_vector_type(4))) float f32x4;
typedef __attribute__((ext_vector_type(8))) short short8;
typedef __attribute__((ext_vector_type(8))) unsigned short ushort8;

constexpr int CB = 32;
constexpr int CS = 2048;
constexpr int CD = 1024;
constexpr int CU = 1024;
constexpr int CM = CB * CS;   // 65536

DEVFN unsigned f2bf_u(float f) {
    unsigned u = __float_as_uint(f);
    return (u + 0x7FFFu + ((u >> 16) & 1u)) >> 16;   // RNE f32->bf16
}
DEVFN unsigned f2bf_pack(float lo, float hi) {
    return f2bf_u(lo) | (f2bf_u(hi) << 16);
}
DEVFN float tanh_fast(float x) {
    float e = exp2f(x * 2.885390081777927f);
    return 1.0f - 2.0f * __builtin_amdgcn_rcpf(e + 1.0f);
}

// ---- bias = b1 + b2 + q@W2, two-stage split-D ----
__global__ void k_bias1(const float* __restrict__ q, const float* __restrict__ W2,
                        float* __restrict__ bpart) {
    int dc = blockIdx.x, b = blockIdx.y;   // 8 x 32
    int t = threadIdx.x;                    // 256
    __shared__ float qs[128];
    if (t < 128) qs[t] = q[b * CD + dc * 128 + t];
    __syncthreads();
    float acc0 = 0.f, acc1 = 0.f, acc2 = 0.f, acc3 = 0.f;
    const float* w2 = W2 + (size_t)(dc * 128) * CU + t;
#pragma unroll 4
    for (int d = 0; d < 128; ++d) {
        float qv = qs[d];
        const float* r = w2 + (size_t)d * CU;
        acc0 += qv * r[0];
        acc1 += qv * r[256];
        acc2 += qv * r[512];
        acc3 += qv * r[768];
    }
    float* o = bpart + (size_t)(b * 8 + dc) * CU + t;
    o[0] = acc0; o[256] = acc1; o[512] = acc2; o[768] = acc3;
}

__global__ void k_bias2(const float* __restrict__ bpart, const float* __restrict__ b1,
                        const float* __restrict__ b2, float* __restrict__ bias) {
    int idx = blockIdx.x * 256 + threadIdx.x;   // 32768
    int b = idx >> 10, u = idx & 1023;
    float s = b1[u] + b2[u];
#pragma unroll
    for (int dc = 0; dc < 8; ++dc) s += bpart[(size_t)(b * 8 + dc) * CU + u];
    bias[idx] = s;
}

// ---- pack W1[D][U] f32 -> bf16, MFMA-B fragment-linear tiles ----
// idx = (kt*4+ut)*8192 + ub*512 + l*8 + j ; d = kt*32 + (l>>4)*8 + j ; u = ut*256 + ub*16 + (l&15)
__global__ void k_packW1(const float* __restrict__ W1, unsigned short* __restrict__ W1p) {
    int tid = blockIdx.x * 256 + threadIdx.x;   // 131072 threads, 8 elems each
    int o8  = tid * 8;
    int l   = (o8 >> 3) & 63;
    int ub  = (o8 >> 9) & 15;
    int ut  = (o8 >> 13) & 3;
    int kt  = o8 >> 15;
    int u  = ut * 256 + ub * 16 + (l & 15);
    int d0 = kt * 32 + (l >> 4) * 8;
    ushort8 v;
#pragma unroll
    for (int j = 0; j < 8; ++j)
        v[j] = (unsigned short)f2bf_u(W1[(size_t)(d0 + j) * CU + u]);
    *(ushort8*)(W1p + o8) = v;
}

// ---- fused score GEMM: BM=64 x U=1024, BK=32, 8 waves (64 rows x 128 cols each).
// B (W1p): global->register direct, double-buffered, coalesced 1KB frag loads (L2-hot).
// A (values): reg-staged f32 -> bf16 frag-linear LDS dbuf (8 KB total).
// One barrier + one lgkmcnt(0) per K-step; B waits are compiler-counted vmcnt.
__global__ __launch_bounds__(512, 2) void k_score(
    const float* __restrict__ values, const unsigned short* __restrict__ W1p,
    const float* __restrict__ bias, const float* __restrict__ V,
    float* __restrict__ score) {
    __shared__ __align__(16) char smem[8192];   // A dbuf 2*4KB; red[] reuses buf0

    const int t = threadIdx.x;
    const int w = t >> 6, l = t & 63;
    const int m0 = blockIdx.x * 64;
    const int bb = m0 >> 11;              // batch (64 divides S)

    // A stage: thread t loads values[m0 + t/8][kt*32 + (t&7)*4 ..+4] (f32x4)
    const float* aSrcT = values + (size_t)(m0 + (t >> 3)) * CD + (t & 7) * 4;
    const int aWrByte = (t >> 7) * 1024
                      + (((t >> 3) & 15) | (((t >> 1) & 3) << 4)) * 16
                      + (t & 1) * 8;
    // B: wave w's 128-col slice, frag jj at bSrc + kt*32768 + jj*512 (1KB coalesced)
    const unsigned short* bSrc = W1p + (size_t)w * 4096 + l * 8;

    f32x4 zero4 = {0.f, 0.f, 0.f, 0.f};
    f32x4 acc[4][8];
#pragma unroll
    for (int i = 0; i < 4; ++i)
#pragma unroll
        for (int j = 0; j < 8; ++j) acc[i][j] = zero4;

    short8 bFA[8], bFB[8];
    f32x4 aH0, aH1;

    // prologue: B(0)->bFA ; A(0),A(1)->regs ; write A(0)->buf0 ; barrier
    {
#pragma unroll
        for (int jj = 0; jj < 8; ++jj)
            bFA[jj] = *(const short8*)(bSrc + jj * 512);
        aH0 = *(const f32x4*)(aSrcT);
        aH1 = *(const f32x4*)(aSrcT + 32);
        uint2 pk;
        pk.x = f2bf_pack(aH0[0], aH0[1]);
        pk.y = f2bf_pack(aH0[2], aH0[3]);
        *(uint2*)(smem + aWrByte) = pk;
        asm volatile("s_waitcnt lgkmcnt(0)" ::: "memory");
        asm volatile("s_barrier" ::: "memory");
    }

#define SCORE_BODY(KT, BF_CUR, BF_NXT, AH_LD, AH_WR, DO_LDB, DO_LDA, DO_WR)        \
    {                                                                               \
        if (DO_LDB) {                                                               \
            const unsigned short* bs = bSrc + (size_t)((KT) + 1) * 32768;           \
            _Pragma("unroll")                                                       \
            for (int jj = 0; jj < 8; ++jj)                                          \
                BF_NXT[jj] = *(const short8*)(bs + jj * 512);                       \
        }                                                                           \
        if (DO_LDA) AH_LD = *(const f32x4*)(aSrcT + ((KT) + 2) * 32);               \
        const char* aB = smem + ((KT) & 1) * 4096;                                  \
        short8 aF[4];                                                               \
        _Pragma("unroll")                                                           \
        for (int i = 0; i < 4; ++i)                                                 \
            aF[i] = *(const short8*)(aB + i * 1024 + l * 16);                       \
        __builtin_amdgcn_s_setprio(1);                                              \
        _Pragma("unroll")                                                           \
        for (int i = 0; i < 4; ++i)                                                 \
            _Pragma("unroll")                                                       \
            for (int j = 0; j < 8; ++j)                                             \
                acc[i][j] = __builtin_amdgcn_mfma_f32_16x16x32_bf16(                \
                    aF[i], BF_CUR[j], acc[i][j], 0, 0, 0);                          \
        __builtin_amdgcn_s_setprio(0);                                              \
        if (DO_WR) {                                                                \
            uint2 pk;                                                               \
            pk.x = f2bf_pack(AH_WR[0], AH_WR[1]);                                   \
            pk.y = f2bf_pack(AH_WR[2], AH_WR[3]);                                   \
            *(uint2*)(smem + (((KT) + 1) & 1) * 4096 + aWrByte) = pk;               \
        }                                                                           \
        asm volatile("s_waitcnt lgkmcnt(0)" ::: "memory");                          \
        asm volatile("s_barrier" ::: "memory");                                     \
    }

    for (int kt = 0; kt < 30; kt += 2) {
        SCORE_BODY(kt,     bFA, bFB, aH0, aH1, 1, 1, 1)
        SCORE_BODY(kt + 1, bFB, bFA, aH1, aH0, 1, 1, 1)
    }
    SCORE_BODY(30, bFA, bFB, aH0, aH1, 1, 0, 1)   // load B(31), write A(31)=aH1
    SCORE_BODY(31, bFB, bFA, aH1, aH0, 0, 0, 0)
#undef SCORE_BODY

    // epilogue: score[m0+r] = sum_u V[u]*tanh(z[r][u] + bias[bb][u])
    float part[4][4];
#pragma unroll
    for (int i = 0; i < 4; ++i)
#pragma unroll
        for (int rr = 0; rr < 4; ++rr) part[i][rr] = 0.f;

#pragma unroll
    for (int j = 0; j < 8; ++j) {
        int col = w * 128 + j * 16 + (l & 15);
        float vv = V[col];
        float bz = bias[bb * CU + col];
#pragma unroll
        for (int i = 0; i < 4; ++i)
#pragma unroll
            for (int rr = 0; rr < 4; ++rr)
                part[i][rr] += vv * tanh_fast(acc[i][j][rr] + bz);
    }

    __syncthreads();
    float* red = (float*)smem;    // [8][64] f32, reuses buf0 region
#pragma unroll
    for (int i = 0; i < 4; ++i)
#pragma unroll
        for (int rr = 0; rr < 4; ++rr) {
            float v = part[i][rr];
            v += __shfl_xor(v, 1);
            v += __shfl_xor(v, 2);
            v += __shfl_xor(v, 4);
            v += __shfl_xor(v, 8);
            if ((l & 15) == 0)
                red[w * 64 + i * 16 + (l >> 4) * 4 + rr] = v;
        }
    __syncthreads();
    if (t < 64) {
        float s = 0.f;
#pragma unroll
        for (int ww = 0; ww < 8; ++ww) s += red[ww * 64 + t];
        score[m0 + t] = s;
    }
}

// ---- softmax over S per batch ----
__global__ void k_softmax(const float* __restrict__ score, float* __restrict__ wts) {
    int b = blockIdx.x, t = threadIdx.x;   // 1024 threads
    int i0 = b * CS + t, i1 = i0 + 1024;
    float s0 = score[i0];
    float s1 = score[i1];
    __shared__ float red[16];
    int wv = t >> 6, ln = t & 63;
    float m = fmaxf(s0, s1);
#pragma unroll
    for (int o = 32; o >= 1; o >>= 1) m = fmaxf(m, __shfl_xor(m, o));
    if (ln == 0) red[wv] = m;
    __syncthreads();
    float M = red[0];
#pragma unroll
    for (int k = 1; k < 16; ++k) M = fmaxf(M, red[k]);
    float e0 = __expf(s0 - M), e1 = __expf(s1 - M);
    float sm = e0 + e1;
#pragma unroll
    for (int o = 32; o >= 1; o >>= 1) sm += __shfl_xor(sm, o);
    __syncthreads();
    if (ln == 0) red[wv] = sm;
    __syncthreads();
    float T = 0.f;
#pragma unroll
    for (int k = 0; k < 16; ++k) T += red[k];
    float inv = 1.0f / T;
    wts[i0] = e0 * inv;
    wts[i1] = e1 * inv;
}

// ---- context ----
__global__ void k_ctx_part(const float* __restrict__ values, const float* __restrict__ wts,
                           float* __restrict__ part) {
    int b = blockIdx.y, sc = blockIdx.x;   // 32 x 32
    int t = threadIdx.x;                    // 256, float4 each -> full D
    const float* vb = values + ((size_t)b * CS + sc * 64) * CD + t * 4;
    const float* wb = wts + b * CS + sc * 64;
    f32x4 a = {0.f, 0.f, 0.f, 0.f};
#pragma unroll 8
    for (int s = 0; s < 64; ++s) {
        float wgt = wb[s];
        f32x4 v = *(const f32x4*)(vb + (size_t)s * CD);
        a += v * wgt;
    }
    *(f32x4*)(part + (size_t)(b * 32 + sc) * CD + t * 4) = a;
}

__global__ void k_ctx_red(const float* __restrict__ part, float* __restrict__ ctx) {
    int idx = blockIdx.x * 256 + threadIdx.x;   // 32768
    int b = idx >> 10, d = idx & 1023;
    float s = 0.f;
#pragma unroll 8
    for (int c = 0; c < 32; ++c) s += part[(size_t)(b * 32 + c) * CD + d];
    ctx[idx] = s;
}

extern "C" void kernel_launch(void* const* d_in, const int* in_sizes, int n_in,
                              void* d_out, int out_size, void* d_ws, size_t ws_size,
                              hipStream_t stream) {
    const float* query  = (const float*)d_in[0];
    const float* values = (const float*)d_in[1];
    const float* W1     = (const float*)d_in[2];
    const float* b1     = (const float*)d_in[3];
    const float* W2     = (const float*)d_in[4];
    const float* b2     = (const float*)d_in[5];
    const float* V      = (const float*)d_in[6];
    // d_in[7] = bV: softmax shift-invariant, score not an output -> unused

    float* out = (float*)d_out;
    float* ctx = out;            // [32][1024]
    float* wts = out + 32768;    // [32][2048]

    char* ws = (char*)d_ws;
    float*          score = (float*)ws;                                        // 256 KB (1 MB reserved)
    float*          bias  = (float*)(ws + (1 << 20));                          // 128 KB
    unsigned short* W1p   = (unsigned short*)(ws + (1 << 20) + (1 << 17));     // 2 MB
    float*          part  = (float*)(ws + (1 << 20) + (1 << 17) + (1 << 21));  // 4 MB
    float*          bpart = part;   // 1 MB, consumed before k_ctx_part

    k_bias1<<<dim3(8, 32), 256, 0, stream>>>(query, W2, bpart);
    k_bias2<<<128, 256, 0, stream>>>(bpart, b1, b2, bias);
    k_packW1<<<512, 256, 0, stream>>>(W1, W1p);
    k_score<<<1024, 512, 0, stream>>>(values, W1p, bias, V, score);
    k_softmax<<<32, 1024, 0, stream>>>(score, wts);
    k_ctx_part<<<dim3(32, 32), 256, 0, stream>>>(values, wts, part);
    k_ctx_red<<<128, 256, 0, stream>>>(part, ctx);
}

// Round 5
// 221.575 us; speedup vs baseline: 5.1451x; 1.0640x over previous
//
#include <hip/hip_runtime.h>

#define DEVFN __device__ __forceinline__
#define GLOBAL_AS __attribute__((address_space(1)))
#define LDS_AS __attribute__((address_space(3)))

typedef __attribute__((ext_vector_type(4))) float f32x4;
typedef __attribute__((ext_vector_type(8))) short short8;
typedef __attribute__((ext_vector_type(8))) unsigned short ushort8;

constexpr int CB = 32;
constexpr int CS = 2048;
constexpr int CD = 1024;
constexpr int CU = 1024;
constexpr int CM = CB * CS;   // 65536

DEVFN unsigned f2bf_u(float f) {
    unsigned u = __float_as_uint(f);
    return (u + 0x7FFFu + ((u >> 16) & 1u)) >> 16;   // RNE f32->bf16
}
DEVFN unsigned f2bf_pack(float lo, float hi) {
    return f2bf_u(lo) | (f2bf_u(hi) << 16);
}
DEVFN float tanh_fast(float x) {
    float e = exp2f(x * 2.885390081777927f);
    return 1.0f - 2.0f * __builtin_amdgcn_rcpf(e + 1.0f);
}

// ---- bias = b1 + b2 + q@W2, two-stage split-D ----
__global__ void k_bias1(const float* __restrict__ q, const float* __restrict__ W2,
                        float* __restrict__ bpart) {
    int dc = blockIdx.x, b = blockIdx.y;   // 8 x 32
    int t = threadIdx.x;                    // 256
    __shared__ float qs[128];
    if (t < 128) qs[t] = q[b * CD + dc * 128 + t];
    __syncthreads();
    float acc0 = 0.f, acc1 = 0.f, acc2 = 0.f, acc3 = 0.f;
    const float* w2 = W2 + (size_t)(dc * 128) * CU + t;
#pragma unroll 4
    for (int d = 0; d < 128; ++d) {
        float qv = qs[d];
        const float* r = w2 + (size_t)d * CU;
        acc0 += qv * r[0];
        acc1 += qv * r[256];
        acc2 += qv * r[512];
        acc3 += qv * r[768];
    }
    float* o = bpart + (size_t)(b * 8 + dc) * CU + t;
    o[0] = acc0; o[256] = acc1; o[512] = acc2; o[768] = acc3;
}

__global__ void k_bias2(const float* __restrict__ bpart, const float* __restrict__ b1,
                        const float* __restrict__ b2, float* __restrict__ bias) {
    int idx = blockIdx.x * 256 + threadIdx.x;   // 32768
    int b = idx >> 10, u = idx & 1023;
    float s = b1[u] + b2[u];
#pragma unroll
    for (int dc = 0; dc < 8; ++dc) s += bpart[(size_t)(b * 8 + dc) * CU + u];
    bias[idx] = s;
}

// ---- pack W1[D][U] f32 -> bf16, MFMA-B fragment-linear tiles ----
// idx = (kt*4+ut)*8192 + ub*512 + l*8 + j ; d = kt*32 + (l>>4)*8 + j ; u = ut*256 + ub*16 + (l&15)
__global__ void k_packW1(const float* __restrict__ W1, unsigned short* __restrict__ W1p) {
    int tid = blockIdx.x * 256 + threadIdx.x;   // 131072 threads, 8 elems each
    int o8  = tid * 8;
    int l   = (o8 >> 3) & 63;
    int ub  = (o8 >> 9) & 15;
    int ut  = (o8 >> 13) & 3;
    int kt  = o8 >> 15;
    int u  = ut * 256 + ub * 16 + (l & 15);
    int d0 = kt * 32 + (l >> 4) * 8;
    ushort8 v;
#pragma unroll
    for (int j = 0; j < 8; ++j)
        v[j] = (unsigned short)f2bf_u(W1[(size_t)(d0 + j) * CU + u]);
    *(ushort8*)(W1p + o8) = v;
}

// ---- fused score GEMM: BM=64 x U=1024, BK=32, 8 waves (64 rows x 128 cols each).
// B (W1p): global->register direct, double-buffered (must stay L2-resident).
// A (values): NON-TEMPORAL loads (keep W1p in L2), reg-staged f32->bf16,
//             XOR-swizzled frag-linear LDS dbuf (conflict-free write+read).
__global__ __launch_bounds__(512, 2) void k_score(
    const float* __restrict__ values, const unsigned short* __restrict__ W1p,
    const float* __restrict__ bias, const float* __restrict__ V,
    float* __restrict__ score) {
    __shared__ __align__(16) char smem[8192];   // A dbuf 2*4KB; red[] reuses buf0

    const int t = threadIdx.x;
    const int w = t >> 6, l = t & 63;
    const int m0 = blockIdx.x * 64;
    const int bb = m0 >> 11;              // batch (64 divides S)

    // A stage: thread t loads values[m0 + t/8][kt*32 + (t&7)*4 ..+4] (f32x4)
    const float* aSrcT = values + (size_t)(m0 + (t >> 3)) * CD + (t & 7) * 4;
    // swizzled frag-linear write slot: frag = t>>7, row = (t>>3)&15, khi = (t&7)>>1
    // slot = (row ^ khi) | (khi<<4)  -> 8-thread write group spans 16 banks
    const int aWrByte = (t >> 7) * 1024
                      + (((((t >> 3) & 15) ^ ((t & 7) >> 1)) | (((t & 7) >> 1) << 4)) << 4)
                      + (t & 1) * 8;
    // swizzled read slot for lane l: slot = ((l&15) ^ (l>>4)) | ((l>>4)<<4)
    const int aRdOff = ((((l & 15) ^ (l >> 4)) | ((l >> 4) << 4)) << 4);
    // B: wave w's 128-col slice, frag jj at bSrc + kt*32768 + jj*512 (1KB coalesced)
    const unsigned short* bSrc = W1p + (size_t)w * 4096 + l * 8;

    f32x4 zero4 = {0.f, 0.f, 0.f, 0.f};
    f32x4 acc[4][8];
#pragma unroll
    for (int i = 0; i < 4; ++i)
#pragma unroll
        for (int j = 0; j < 8; ++j) acc[i][j] = zero4;

    short8 bFA[8], bFB[8];
    f32x4 aH0, aH1;

    // prologue: B(0)->bFA ; A(0),A(1)->regs ; write A(0)->buf0 ; barrier
    {
#pragma unroll
        for (int jj = 0; jj < 8; ++jj)
            bFA[jj] = *(const short8*)(bSrc + jj * 512);
        aH0 = __builtin_nontemporal_load((const f32x4*)aSrcT);
        aH1 = __builtin_nontemporal_load((const f32x4*)(aSrcT + 32));
        uint2 pk;
        pk.x = f2bf_pack(aH0[0], aH0[1]);
        pk.y = f2bf_pack(aH0[2], aH0[3]);
        *(uint2*)(smem + aWrByte) = pk;
        asm volatile("s_waitcnt lgkmcnt(0)" ::: "memory");
        asm volatile("s_barrier" ::: "memory");
    }

#define SCORE_BODY(KT, BF_CUR, BF_NXT, AH_LD, AH_WR, DO_LDB, DO_LDA, DO_WR)        \
    {                                                                               \
        if (DO_LDB) {                                                               \
            const unsigned short* bs = bSrc + (size_t)((KT) + 1) * 32768;           \
            _Pragma("unroll")                                                       \
            for (int jj = 0; jj < 8; ++jj)                                          \
                BF_NXT[jj] = *(const short8*)(bs + jj * 512);                       \
        }                                                                           \
        if (DO_LDA)                                                                 \
            AH_LD = __builtin_nontemporal_load(                                     \
                (const f32x4*)(aSrcT + ((KT) + 2) * 32));                           \
        const char* aB = smem + ((KT) & 1) * 4096;                                  \
        short8 aF[4];                                                               \
        _Pragma("unroll")                                                           \
        for (int i = 0; i < 4; ++i)                                                 \
            aF[i] = *(const short8*)(aB + i * 1024 + aRdOff);                       \
        __builtin_amdgcn_s_setprio(1);                                              \
        _Pragma("unroll")                                                           \
        for (int i = 0; i < 4; ++i)                                                 \
            _Pragma("unroll")                                                       \
            for (int j = 0; j < 8; ++j)                                             \
                acc[i][j] = __builtin_amdgcn_mfma_f32_16x16x32_bf16(                \
                    aF[i], BF_CUR[j], acc[i][j], 0, 0, 0);                          \
        __builtin_amdgcn_s_setprio(0);                                              \
        if (DO_WR) {                                                                \
            uint2 pk;                                                               \
            pk.x = f2bf_pack(AH_WR[0], AH_WR[1]);                                   \
            pk.y = f2bf_pack(AH_WR[2], AH_WR[3]);                                   \
            *(uint2*)(smem + (((KT) + 1) & 1) * 4096 + aWrByte) = pk;               \
        }                                                                           \
        asm volatile("s_waitcnt lgkmcnt(0)" ::: "memory");                          \
        asm volatile("s_barrier" ::: "memory");                                     \
    }

    for (int kt = 0; kt < 30; kt += 2) {
        SCORE_BODY(kt,     bFA, bFB, aH0, aH1, 1, 1, 1)
        SCORE_BODY(kt + 1, bFB, bFA, aH1, aH0, 1, 1, 1)
    }
    SCORE_BODY(30, bFA, bFB, aH0, aH1, 1, 0, 1)   // load B(31), write A(31)=aH1
    SCORE_BODY(31, bFB, bFA, aH1, aH0, 0, 0, 0)
#undef SCORE_BODY

    // epilogue: score[m0+r] = sum_u V[u]*tanh(z[r][u] + bias[bb][u])
    float part[4][4];
#pragma unroll
    for (int i = 0; i < 4; ++i)
#pragma unroll
        for (int rr = 0; rr < 4; ++rr) part[i][rr] = 0.f;

#pragma unroll
    for (int j = 0; j < 8; ++j) {
        int col = w * 128 + j * 16 + (l & 15);
        float vv = V[col];
        float bz = bias[bb * CU + col];
#pragma unroll
        for (int i = 0; i < 4; ++i)
#pragma unroll
            for (int rr = 0; rr < 4; ++rr)
                part[i][rr] += vv * tanh_fast(acc[i][j][rr] + bz);
    }

    __syncthreads();
    float* red = (float*)smem;    // [8][64] f32, reuses buf0 region
#pragma unroll
    for (int i = 0; i < 4; ++i)
#pragma unroll
        for (int rr = 0; rr < 4; ++rr) {
            float v = part[i][rr];
            v += __shfl_xor(v, 1);
            v += __shfl_xor(v, 2);
            v += __shfl_xor(v, 4);
            v += __shfl_xor(v, 8);
            if ((l & 15) == 0)
                red[w * 64 + i * 16 + (l >> 4) * 4 + rr] = v;
        }
    __syncthreads();
    if (t < 64) {
        float s = 0.f;
#pragma unroll
        for (int ww = 0; ww < 8; ++ww) s += red[ww * 64 + t];
        score[m0 + t] = s;
    }
}

// ---- softmax over S per batch ----
__global__ void k_softmax(const float* __restrict__ score, float* __restrict__ wts) {
    int b = blockIdx.x, t = threadIdx.x;   // 1024 threads
    int i0 = b * CS + t, i1 = i0 + 1024;
    float s0 = score[i0];
    float s1 = score[i1];
    __shared__ float red[16];
    int wv = t >> 6, ln = t & 63;
    float m = fmaxf(s0, s1);
#pragma unroll
    for (int o = 32; o >= 1; o >>= 1) m = fmaxf(m, __shfl_xor(m, o));
    if (ln == 0) red[wv] = m;
    __syncthreads();
    float M = red[0];
#pragma unroll
    for (int k = 1; k < 16; ++k) M = fmaxf(M, red[k]);
    float e0 = __expf(s0 - M), e1 = __expf(s1 - M);
    float sm = e0 + e1;
#pragma unroll
    for (int o = 32; o >= 1; o >>= 1) sm += __shfl_xor(sm, o);
    __syncthreads();
    if (ln == 0) red[wv] = sm;
    __syncthreads();
    float T = 0.f;
#pragma unroll
    for (int k = 0; k < 16; ++k) T += red[k];
    float inv = 1.0f / T;
    wts[i0] = e0 * inv;
    wts[i1] = e1 * inv;
}

// ---- context ----
__global__ void k_ctx_part(const float* __restrict__ values, const float* __restrict__ wts,
                           float* __restrict__ part) {
    int b = blockIdx.y, sc = blockIdx.x;   // 32 x 32
    int t = threadIdx.x;                    // 256, float4 each -> full D
    const float* vb = values + ((size_t)b * CS + sc * 64) * CD + t * 4;
    const float* wb = wts + b * CS + sc * 64;
    f32x4 a = {0.f, 0.f, 0.f, 0.f};
#pragma unroll 8
    for (int s = 0; s < 64; ++s) {
        float wgt = wb[s];
        f32x4 v = *(const f32x4*)(vb + (size_t)s * CD);
        a += v * wgt;
    }
    *(f32x4*)(part + (size_t)(b * 32 + sc) * CD + t * 4) = a;
}

__global__ void k_ctx_red(const float* __restrict__ part, float* __restrict__ ctx) {
    int idx = blockIdx.x * 256 + threadIdx.x;   // 32768
    int b = idx >> 10, d = idx & 1023;
    float s = 0.f;
#pragma unroll 8
    for (int c = 0; c < 32; ++c) s += part[(size_t)(b * 32 + c) * CD + d];
    ctx[idx] = s;
}

extern "C" void kernel_launch(void* const* d_in, const int* in_sizes, int n_in,
                              void* d_out, int out_size, void* d_ws, size_t ws_size,
                              hipStream_t stream) {
    const float* query  = (const float*)d_in[0];
    const float* values = (const float*)d_in[1];
    const float* W1     = (const float*)d_in[2];
    const float* b1     = (const float*)d_in[3];
    const float* W2     = (const float*)d_in[4];
    const float* b2     = (const float*)d_in[5];
    const float* V      = (const float*)d_in[6];
    // d_in[7] = bV: softmax shift-invariant, score not an output -> unused

    float* out = (float*)d_out;
    float* ctx = out;            // [32][1024]
    float* wts = out + 32768;    // [32][2048]

    char* ws = (char*)d_ws;
    float*          score = (float*)ws;                                        // 256 KB (1 MB reserved)
    float*          bias  = (float*)(ws + (1 << 20));                          // 128 KB
    unsigned short* W1p   = (unsigned short*)(ws + (1 << 20) + (1 << 17));     // 2 MB
    float*          part  = (float*)(ws + (1 << 20) + (1 << 17) + (1 << 21));  // 4 MB
    float*          bpart = part;   // 1 MB, consumed before k_ctx_part

    k_bias1<<<dim3(8, 32), 256, 0, stream>>>(query, W2, bpart);
    k_bias2<<<128, 256, 0, stream>>>(bpart, b1, b2, bias);
    k_packW1<<<512, 256, 0, stream>>>(W1, W1p);
    k_score<<<1024, 512, 0, stream>>>(values, W1p, bias, V, score);
    k_softmax<<<32, 1024, 0, stream>>>(score, wts);
    k_ctx_part<<<dim3(32, 32), 256, 0, stream>>>(values, wts, part);
    k_ctx_red<<<128, 256, 0, stream>>>(part, ctx);
}